// Round 2
// baseline (55.394 us; speedup 1.0000x reference)
//
#include <hip/hip_runtime.h>
#include <math.h>

#define AMP_C 100.0f
#define NSD_SCALE_C 500.0f
#define NSD_SLOPE_C 10.0f
#define TWO_PI_C 6.2831853071795864769f

typedef float v4f __attribute__((ext_vector_type(4)));

// Single fused kernel: each thread
//   1. issues its 3 float4 h-loads (48B = 2 rows) first,
//   2. redundantly computes the 22 collapsed coefficients
//      (A=-M^-1K, B=-M^-1C, M^-1[:,0], -AMP*sin(2pi t)) while loads fly,
//   3. computes [v, a] for its 2 rows,
//   4. writes 3 float4 with NON-TEMPORAL stores so the output does not
//      evict the (L3-resident) input across graph replays.
__global__ __launch_bounds__(256) void fused_kernel(
        const v4f* __restrict__ h4,
        v4f* __restrict__ o4,
        const float* __restrict__ hs,   // scalar views for odd tail
        float* __restrict__ os,
        const float* __restrict__ tp,
        const float* __restrict__ Mp,
        const float* __restrict__ Kp,
        const float* __restrict__ Cp,
        int npairs, int nrows) {
    const int i = blockIdx.x * blockDim.x + threadIdx.x;
    const bool main_lane = (i < npairs);
    const size_t b = (size_t)3 * (size_t)i;

    v4f q0 = {}, q1 = {}, q2 = {};
    if (main_lane) {            // issue streaming loads ASAP
        q0 = h4[b + 0];
        q1 = h4[b + 1];
        q2 = h4[b + 2];
    }

    // ---- coefficient computation (uniform, hidden under memory latency) ----
    float m00 = Mp[0], m01 = Mp[1], m02 = Mp[2];
    float m10 = Mp[3], m11 = Mp[4], m12 = Mp[5];
    float m20 = Mp[6], m21 = Mp[7], m22 = Mp[8];
    float det = m00 * (m11 * m22 - m12 * m21)
              - m01 * (m10 * m22 - m12 * m20)
              + m02 * (m10 * m21 - m11 * m20);
    float id = 1.0f / det;
    float inv[9];
    inv[0] =  (m11 * m22 - m12 * m21) * id;
    inv[1] = -(m01 * m22 - m02 * m21) * id;
    inv[2] =  (m01 * m12 - m02 * m11) * id;
    inv[3] = -(m10 * m22 - m12 * m20) * id;
    inv[4] =  (m00 * m22 - m02 * m20) * id;
    inv[5] = -(m00 * m12 - m02 * m10) * id;
    inv[6] =  (m10 * m21 - m11 * m20) * id;
    inv[7] = -(m00 * m21 - m01 * m20) * id;
    inv[8] =  (m00 * m11 - m01 * m10) * id;

    float A[9], Bc[9];
#pragma unroll
    for (int r = 0; r < 3; ++r) {
#pragma unroll
        for (int c = 0; c < 3; ++c) {
            float sK = 0.0f, sC = 0.0f;
#pragma unroll
            for (int k = 0; k < 3; ++k) {
                sK += inv[3 * r + k] * Kp[3 * k + c];
                sC += inv[3 * r + k] * Cp[3 * k + c];
            }
            A[3 * r + c]  = -sK;
            Bc[3 * r + c] = -sC;
        }
    }
    const float mi0 = inv[0], mi1 = inv[3], mi2 = inv[6];
    const float base = -AMP_C * sinf(TWO_PI_C * tp[0]);

    // ---- main path: 2 rows per thread ----
    if (main_lane) {
        // row0: x=(q0[0],q0[1],q0[2]) v=(q0[3],q1[0],q1[1])
        // row1: x=(q1[2],q1[3],q2[0]) v=(q2[1],q2[2],q2[3])
        float x[2][3] = {{q0[0], q0[1], q0[2]}, {q1[2], q1[3], q2[0]}};
        float v[2][3] = {{q0[3], q1[0], q1[1]}, {q2[1], q2[2], q2[3]}};
        float a[2][3];
#pragma unroll
        for (int r = 0; r < 2; ++r) {
            float f = -NSD_SCALE_C * tanhf(NSD_SLOPE_C * x[r][0]);
            a[r][0] = A[0] * x[r][0] + A[1] * x[r][1] + A[2] * x[r][2]
                    + Bc[0] * v[r][0] + Bc[1] * v[r][1] + Bc[2] * v[r][2]
                    + base + f * mi0;
            a[r][1] = A[3] * x[r][0] + A[4] * x[r][1] + A[5] * x[r][2]
                    + Bc[3] * v[r][0] + Bc[4] * v[r][1] + Bc[5] * v[r][2]
                    + base + f * mi1;
            a[r][2] = A[6] * x[r][0] + A[7] * x[r][1] + A[8] * x[r][2]
                    + Bc[6] * v[r][0] + Bc[7] * v[r][1] + Bc[8] * v[r][2]
                    + base + f * mi2;
        }
        v4f oa = {v[0][0], v[0][1], v[0][2], a[0][0]};
        v4f ob = {a[0][1], a[0][2], v[1][0], v[1][1]};
        v4f oc = {v[1][2], a[1][0], a[1][1], a[1][2]};
        __builtin_nontemporal_store(oa, &o4[b + 0]);
        __builtin_nontemporal_store(ob, &o4[b + 1]);
        __builtin_nontemporal_store(oc, &o4[b + 2]);
    } else if (i == npairs && (nrows & 1)) {
        // odd tail: last row, scalar path
        const size_t r0 = (size_t)(nrows - 1) * 6;
        float x0 = hs[r0 + 0], x1 = hs[r0 + 1], x2 = hs[r0 + 2];
        float v0 = hs[r0 + 3], v1 = hs[r0 + 4], v2 = hs[r0 + 5];
        float f = -NSD_SCALE_C * tanhf(NSD_SLOPE_C * x0);
        float a0 = A[0]*x0 + A[1]*x1 + A[2]*x2 + Bc[0]*v0 + Bc[1]*v1 + Bc[2]*v2 + base + f*mi0;
        float a1 = A[3]*x0 + A[4]*x1 + A[5]*x2 + Bc[3]*v0 + Bc[4]*v1 + Bc[5]*v2 + base + f*mi1;
        float a2 = A[6]*x0 + A[7]*x1 + A[8]*x2 + Bc[6]*v0 + Bc[7]*v1 + Bc[8]*v2 + base + f*mi2;
        os[r0 + 0] = v0; os[r0 + 1] = v1; os[r0 + 2] = v2;
        os[r0 + 3] = a0; os[r0 + 4] = a1; os[r0 + 5] = a2;
    }
}

extern "C" void kernel_launch(void* const* d_in, const int* in_sizes, int n_in,
                              void* d_out, int out_size, void* d_ws, size_t ws_size,
                              hipStream_t stream) {
    const float* t = (const float*)d_in[0];
    const float* h = (const float*)d_in[1];
    const float* M = (const float*)d_in[2];
    const float* K = (const float*)d_in[3];
    const float* C = (const float*)d_in[4];
    float* out = (float*)d_out;

    const int nrows = in_sizes[1] / 6;
    const int npairs = nrows / 2;
    const int total = npairs + (nrows & 1);
    const int block = 256;
    const int grid = (total + block - 1) / block;

    fused_kernel<<<grid, block, 0, stream>>>(
        (const v4f*)h, (v4f*)out, h, out, t, M, K, C, npairs, nrows);
}

// Round 3
// 35.107 us; speedup vs baseline: 1.5779x; 1.5779x over previous
//
#include <hip/hip_runtime.h>
#include <math.h>

#define AMP_C 100.0f
#define NSD_SCALE_C 500.0f
#define NSD_SLOPE_C 10.0f
#define TWO_PI_C 6.2831853071795864769f

typedef float v4f __attribute__((ext_vector_type(4)));

#define ROWS_PER_BLOCK 512   // 256 threads x 2 rows
#define F4_PER_BLOCK   768   // 512 rows * 6 floats / 4

// LDS-staged fully-coalesced streaming map.
// Phase 1: 3x lane-contiguous float4 global loads -> LDS (12 KB).
// Phase 2: each thread reads its 2 rows (3x ds_read_b128, word base 12t
//          -> uniform over all 8 bank groups, conflict-free), computes
//          [v, a], writes back in place.
// Phase 3: 3x lane-contiguous float4 stores from LDS.
__global__ __launch_bounds__(256) void fused_kernel(
        const v4f* __restrict__ h4,
        v4f* __restrict__ o4,
        const float* __restrict__ hs,   // scalar views for tail
        float* __restrict__ os,
        const float* __restrict__ tp,
        const float* __restrict__ Mp,
        const float* __restrict__ Kp,
        const float* __restrict__ Cp,
        int nrows) {
    __shared__ float smem[ROWS_PER_BLOCK * 6];
    v4f* s4 = (v4f*)smem;

    const int tid = threadIdx.x;
    const int row_base = blockIdx.x * ROWS_PER_BLOCK;
    const int rows_here = nrows - row_base;   // >= 1
    const bool full = (rows_here >= ROWS_PER_BLOCK);

    // ---- phase 1: issue coalesced loads ASAP ----
    v4f q0 = {}, q1 = {}, q2 = {};
    const size_t f4base = (size_t)blockIdx.x * F4_PER_BLOCK;
    if (full) {
        q0 = h4[f4base + tid];
        q1 = h4[f4base + 256 + tid];
        q2 = h4[f4base + 512 + tid];
    }

    // ---- coefficient computation (uniform, overlaps load latency) ----
    float m00 = Mp[0], m01 = Mp[1], m02 = Mp[2];
    float m10 = Mp[3], m11 = Mp[4], m12 = Mp[5];
    float m20 = Mp[6], m21 = Mp[7], m22 = Mp[8];
    float det = m00 * (m11 * m22 - m12 * m21)
              - m01 * (m10 * m22 - m12 * m20)
              + m02 * (m10 * m21 - m11 * m20);
    float id = 1.0f / det;
    float inv[9];
    inv[0] =  (m11 * m22 - m12 * m21) * id;
    inv[1] = -(m01 * m22 - m02 * m21) * id;
    inv[2] =  (m01 * m12 - m02 * m11) * id;
    inv[3] = -(m10 * m22 - m12 * m20) * id;
    inv[4] =  (m00 * m22 - m02 * m20) * id;
    inv[5] = -(m00 * m12 - m02 * m10) * id;
    inv[6] =  (m10 * m21 - m11 * m20) * id;
    inv[7] = -(m00 * m21 - m01 * m20) * id;
    inv[8] =  (m00 * m11 - m01 * m10) * id;

    float A[9], Bc[9];
#pragma unroll
    for (int r = 0; r < 3; ++r) {
#pragma unroll
        for (int c = 0; c < 3; ++c) {
            float sK = 0.0f, sC = 0.0f;
#pragma unroll
            for (int k = 0; k < 3; ++k) {
                sK += inv[3 * r + k] * Kp[3 * k + c];
                sC += inv[3 * r + k] * Cp[3 * k + c];
            }
            A[3 * r + c]  = -sK;
            Bc[3 * r + c] = -sC;
        }
    }
    const float mi0 = inv[0], mi1 = inv[3], mi2 = inv[6];
    const float base = -AMP_C * sinf(TWO_PI_C * tp[0]);

    if (full) {
        // stage into LDS
        s4[tid]       = q0;
        s4[256 + tid] = q1;
        s4[512 + tid] = q2;
        __syncthreads();

        // ---- phase 2: 2 rows per thread from LDS ----
        v4f a0 = s4[3 * tid + 0];
        v4f a1 = s4[3 * tid + 1];
        v4f a2 = s4[3 * tid + 2];
        float x[2][3] = {{a0[0], a0[1], a0[2]}, {a1[2], a1[3], a2[0]}};
        float v[2][3] = {{a0[3], a1[0], a1[1]}, {a2[1], a2[2], a2[3]}};
        float a[2][3];
#pragma unroll
        for (int r = 0; r < 2; ++r) {
            float f = -NSD_SCALE_C * tanhf(NSD_SLOPE_C * x[r][0]);
            a[r][0] = A[0] * x[r][0] + A[1] * x[r][1] + A[2] * x[r][2]
                    + Bc[0] * v[r][0] + Bc[1] * v[r][1] + Bc[2] * v[r][2]
                    + base + f * mi0;
            a[r][1] = A[3] * x[r][0] + A[4] * x[r][1] + A[5] * x[r][2]
                    + Bc[3] * v[r][0] + Bc[4] * v[r][1] + Bc[5] * v[r][2]
                    + base + f * mi1;
            a[r][2] = A[6] * x[r][0] + A[7] * x[r][1] + A[8] * x[r][2]
                    + Bc[6] * v[r][0] + Bc[7] * v[r][1] + Bc[8] * v[r][2]
                    + base + f * mi2;
        }
        v4f oa = {v[0][0], v[0][1], v[0][2], a[0][0]};
        v4f ob = {a[0][1], a[0][2], v[1][0], v[1][1]};
        v4f oc = {v[1][2], a[1][0], a[1][1], a[1][2]};
        s4[3 * tid + 0] = oa;
        s4[3 * tid + 1] = ob;
        s4[3 * tid + 2] = oc;
        __syncthreads();

        // ---- phase 3: coalesced store ----
        o4[f4base + tid]       = s4[tid];
        o4[f4base + 256 + tid] = s4[256 + tid];
        o4[f4base + 512 + tid] = s4[512 + tid];
    } else {
        // tail block: scalar per-row path
        for (int r = tid; r < rows_here; r += 256) {
            const size_t r0 = (size_t)(row_base + r) * 6;
            float x0 = hs[r0 + 0], x1 = hs[r0 + 1], x2 = hs[r0 + 2];
            float v0 = hs[r0 + 3], v1 = hs[r0 + 4], v2 = hs[r0 + 5];
            float f = -NSD_SCALE_C * tanhf(NSD_SLOPE_C * x0);
            float o3 = A[0]*x0 + A[1]*x1 + A[2]*x2 + Bc[0]*v0 + Bc[1]*v1 + Bc[2]*v2 + base + f*mi0;
            float o4v = A[3]*x0 + A[4]*x1 + A[5]*x2 + Bc[3]*v0 + Bc[4]*v1 + Bc[5]*v2 + base + f*mi1;
            float o5 = A[6]*x0 + A[7]*x1 + A[8]*x2 + Bc[6]*v0 + Bc[7]*v1 + Bc[8]*v2 + base + f*mi2;
            os[r0 + 0] = v0; os[r0 + 1] = v1; os[r0 + 2] = v2;
            os[r0 + 3] = o3; os[r0 + 4] = o4v; os[r0 + 5] = o5;
        }
    }
}

extern "C" void kernel_launch(void* const* d_in, const int* in_sizes, int n_in,
                              void* d_out, int out_size, void* d_ws, size_t ws_size,
                              hipStream_t stream) {
    const float* t = (const float*)d_in[0];
    const float* h = (const float*)d_in[1];
    const float* M = (const float*)d_in[2];
    const float* K = (const float*)d_in[3];
    const float* C = (const float*)d_in[4];
    float* out = (float*)d_out;

    const int nrows = in_sizes[1] / 6;
    const int grid = (nrows + ROWS_PER_BLOCK - 1) / ROWS_PER_BLOCK;

    fused_kernel<<<grid, 256, 0, stream>>>(
        (const v4f*)h, (v4f*)out, h, out, t, M, K, C, nrows);
}

// Round 4
// 34.684 us; speedup vs baseline: 1.5971x; 1.0122x over previous
//
#include <hip/hip_runtime.h>
#include <math.h>

#define AMP_C 100.0f
#define NSD_SCALE_C 500.0f
#define NSD_SLOPE_C 10.0f
#define TWO_PI_C 6.2831853071795864769f

typedef float v4f __attribute__((ext_vector_type(4)));

#define ROWS_PER_BLOCK 512   // 256 threads x 2 rows
#define F4_PER_BLOCK   768   // 512 rows * 6 floats / 4

// LDS-staged fully-coalesced streaming map.
// Phase 1: 3x global_load_lds_dwordx4 (direct HBM->LDS DMA, no VGPR trip).
//          LDS dest = wave-uniform base + lane*16 (linear layout matches).
// Phase 2: each thread reads its own 2 rows (3x ds_read_b128, thread-private
//          region), computes [v, a], writes back in place (thread-private).
// Phase 3: 3x lane-contiguous float4 stores from LDS.
__global__ __launch_bounds__(256) void fused_kernel(
        const v4f* __restrict__ h4,
        v4f* __restrict__ o4,
        const float* __restrict__ hs,   // scalar views for tail
        float* __restrict__ os,
        const float* __restrict__ tp,
        const float* __restrict__ Mp,
        const float* __restrict__ Kp,
        const float* __restrict__ Cp,
        int nrows) {
    __shared__ float smem[ROWS_PER_BLOCK * 6];
    v4f* s4 = (v4f*)smem;

    const int tid = threadIdx.x;
    const int row_base = blockIdx.x * ROWS_PER_BLOCK;
    const int rows_here = nrows - row_base;   // >= 1
    const bool full = (rows_here >= ROWS_PER_BLOCK);

    // ---- phase 1: direct global->LDS DMA, issued ASAP ----
    const size_t f4base = (size_t)blockIdx.x * F4_PER_BLOCK;
    if (full) {
        const int wbase = tid & ~63;   // wave-uniform lane-0 index
#pragma unroll
        for (int k = 0; k < 3; ++k) {
            __builtin_amdgcn_global_load_lds(
                (const uint32_t*)&h4[f4base + k * 256 + tid],   // per-lane src
                (uint32_t*)&s4[k * 256 + wbase],                // uniform dest
                16, 0, 0);
        }
    }

    // ---- coefficient computation (uniform, overlaps DMA latency) ----
    float m00 = Mp[0], m01 = Mp[1], m02 = Mp[2];
    float m10 = Mp[3], m11 = Mp[4], m12 = Mp[5];
    float m20 = Mp[6], m21 = Mp[7], m22 = Mp[8];
    float det = m00 * (m11 * m22 - m12 * m21)
              - m01 * (m10 * m22 - m12 * m20)
              + m02 * (m10 * m21 - m11 * m20);
    float id = 1.0f / det;
    float inv[9];
    inv[0] =  (m11 * m22 - m12 * m21) * id;
    inv[1] = -(m01 * m22 - m02 * m21) * id;
    inv[2] =  (m01 * m12 - m02 * m11) * id;
    inv[3] = -(m10 * m22 - m12 * m20) * id;
    inv[4] =  (m00 * m22 - m02 * m20) * id;
    inv[5] = -(m00 * m12 - m02 * m10) * id;
    inv[6] =  (m10 * m21 - m11 * m20) * id;
    inv[7] = -(m00 * m21 - m01 * m20) * id;
    inv[8] =  (m00 * m11 - m01 * m10) * id;

    float A[9], Bc[9];
#pragma unroll
    for (int r = 0; r < 3; ++r) {
#pragma unroll
        for (int c = 0; c < 3; ++c) {
            float sK = 0.0f, sC = 0.0f;
#pragma unroll
            for (int k = 0; k < 3; ++k) {
                sK += inv[3 * r + k] * Kp[3 * k + c];
                sC += inv[3 * r + k] * Cp[3 * k + c];
            }
            A[3 * r + c]  = -sK;
            Bc[3 * r + c] = -sC;
        }
    }
    const float mi0 = inv[0], mi1 = inv[3], mi2 = inv[6];
    const float base = -AMP_C * sinf(TWO_PI_C * tp[0]);

    if (full) {
        __syncthreads();   // compiler drains vmcnt before s_barrier

        // ---- phase 2: 2 rows per thread from LDS (thread-private region) ----
        v4f a0 = s4[3 * tid + 0];
        v4f a1 = s4[3 * tid + 1];
        v4f a2 = s4[3 * tid + 2];
        float x[2][3] = {{a0[0], a0[1], a0[2]}, {a1[2], a1[3], a2[0]}};
        float v[2][3] = {{a0[3], a1[0], a1[1]}, {a2[1], a2[2], a2[3]}};
        float a[2][3];
#pragma unroll
        for (int r = 0; r < 2; ++r) {
            float f = -NSD_SCALE_C * tanhf(NSD_SLOPE_C * x[r][0]);
            a[r][0] = A[0] * x[r][0] + A[1] * x[r][1] + A[2] * x[r][2]
                    + Bc[0] * v[r][0] + Bc[1] * v[r][1] + Bc[2] * v[r][2]
                    + base + f * mi0;
            a[r][1] = A[3] * x[r][0] + A[4] * x[r][1] + A[5] * x[r][2]
                    + Bc[3] * v[r][0] + Bc[4] * v[r][1] + Bc[5] * v[r][2]
                    + base + f * mi1;
            a[r][2] = A[6] * x[r][0] + A[7] * x[r][1] + A[8] * x[r][2]
                    + Bc[6] * v[r][0] + Bc[7] * v[r][1] + Bc[8] * v[r][2]
                    + base + f * mi2;
        }
        v4f oa = {v[0][0], v[0][1], v[0][2], a[0][0]};
        v4f ob = {a[0][1], a[0][2], v[1][0], v[1][1]};
        v4f oc = {v[1][2], a[1][0], a[1][1], a[1][2]};
        s4[3 * tid + 0] = oa;
        s4[3 * tid + 1] = ob;
        s4[3 * tid + 2] = oc;
        __syncthreads();

        // ---- phase 3: coalesced store ----
        o4[f4base + tid]       = s4[tid];
        o4[f4base + 256 + tid] = s4[256 + tid];
        o4[f4base + 512 + tid] = s4[512 + tid];
    } else {
        // tail block: scalar per-row path (unused at B=4194304, kept for safety)
        for (int r = tid; r < rows_here; r += 256) {
            const size_t r0 = (size_t)(row_base + r) * 6;
            float x0 = hs[r0 + 0], x1 = hs[r0 + 1], x2 = hs[r0 + 2];
            float v0 = hs[r0 + 3], v1 = hs[r0 + 4], v2 = hs[r0 + 5];
            float f = -NSD_SCALE_C * tanhf(NSD_SLOPE_C * x0);
            float o3  = A[0]*x0 + A[1]*x1 + A[2]*x2 + Bc[0]*v0 + Bc[1]*v1 + Bc[2]*v2 + base + f*mi0;
            float o4v = A[3]*x0 + A[4]*x1 + A[5]*x2 + Bc[3]*v0 + Bc[4]*v1 + Bc[5]*v2 + base + f*mi1;
            float o5  = A[6]*x0 + A[7]*x1 + A[8]*x2 + Bc[6]*v0 + Bc[7]*v1 + Bc[8]*v2 + base + f*mi2;
            os[r0 + 0] = v0; os[r0 + 1] = v1; os[r0 + 2] = v2;
            os[r0 + 3] = o3; os[r0 + 4] = o4v; os[r0 + 5] = o5;
        }
    }
}

extern "C" void kernel_launch(void* const* d_in, const int* in_sizes, int n_in,
                              void* d_out, int out_size, void* d_ws, size_t ws_size,
                              hipStream_t stream) {
    const float* t = (const float*)d_in[0];
    const float* h = (const float*)d_in[1];
    const float* M = (const float*)d_in[2];
    const float* K = (const float*)d_in[3];
    const float* C = (const float*)d_in[4];
    float* out = (float*)d_out;

    const int nrows = in_sizes[1] / 6;
    const int grid = (nrows + ROWS_PER_BLOCK - 1) / ROWS_PER_BLOCK;

    fused_kernel<<<grid, 256, 0, stream>>>(
        (const v4f*)h, (v4f*)out, h, out, t, M, K, C, nrows);
}